// Round 15
// baseline (536.523 us; speedup 1.0000x reference)
//
#include <hip/hip_runtime.h>
#include <cstddef>
#include <cstdint>

#define DEV __device__ __forceinline__

namespace {
constexpr int BATCH = 8;
constexpr int SEQL  = 4096;
constexpr int DM    = 256;   // d_model
constexpr int DS    = 16;    // d_state
constexpr int DI    = 512;   // d_inner
constexpr int NTOK  = BATCH * SEQL;   // 32768
constexpr int TC    = 32;             // scan chunk length
constexpr int NCH   = SEQL / TC;      // 128 chunks per sequence
constexpr float EPSF = 1e-5f;

// workspace offsets (bytes)
constexpr size_t OFF_X   = 0;                                   // fp32 NTOK*DM
constexpr size_t OFF_XPB = OFF_X   + (size_t)NTOK * DM * 4;     // bf16 NTOK*DI (xp -> ygb)
constexpr size_t OFF_ZBB = OFF_XPB + (size_t)NTOK * DI * 2;     // bf16 NTOK*DI (z)
constexpr size_t OFF_XCB = OFF_ZBB + (size_t)NTOK * DI * 2;     // bf16 NTOK*DI (conv out)
constexpr size_t OFF_XLN = OFF_XCB + (size_t)NTOK * DI * 2;     // bf16 NTOK*DM
constexpr size_t OFF_B   = OFF_XLN + (size_t)NTOK * DM * 2;     // fp32 NTOK*DS
constexpr size_t OFF_C   = OFF_B   + (size_t)NTOK * DS * 4;     // fp32 NTOK*DS
constexpr size_t OFF_DTR = OFF_C   + (size_t)NTOK * DS * 4;     // fp32 NTOK
constexpr size_t OFF_HE  = OFF_DTR + (size_t)NTOK * 4;          // fp32 BATCH*DI*NCH*DS
constexpr size_t OFF_DTC = OFF_HE  + (size_t)BATCH * DI * NCH * DS * 4; // fp32 BATCH*DI*NCH
constexpr size_t OFF_WBI = OFF_DTC + (size_t)BATCH * DI * NCH * 4;      // bf16 2*1024*256
constexpr size_t OFF_WBO = OFF_WBI + (size_t)2 * 2 * DI * DM * 2;       // bf16 2*256*512
constexpr size_t OFF_WBX = OFF_WBO + (size_t)2 * DM * DI * 2;           // bf16 2*48*512 (padded)
constexpr size_t OFF_CWT = OFF_WBX + (size_t)2 * 48 * DI * 2;           // fp32 2*4*512 transposed conv w
constexpr size_t WBI_EL  = 2 * 2 * DI * DM;   // 524288
constexpr size_t WBO_EL  = 2 * DM * DI;       // 262144
constexpr int PREP_T1 = (int)(WBI_EL / 4);           // 131072
constexpr int PREP_T2 = PREP_T1 + (int)(WBO_EL / 4); // +65536
constexpr int PREP_T3 = PREP_T2 + 2 * 48 * 512;      // +49152
constexpr int PREP_T4 = PREP_T3 + 2 * 4 * 512;       // +4096 = 249856
} // namespace

typedef __attribute__((ext_vector_type(8))) short short8;
typedef __attribute__((ext_vector_type(4))) float f32x4;

DEV float sigmoidf_(float v) { return 1.0f / (1.0f + __expf(-v)); }
DEV float siluf_(float v)    { return v * sigmoidf_(v); }
DEV float b2f(unsigned short u) {
    union { unsigned int i; float f; } c; c.i = ((unsigned int)u) << 16; return c.f;
}
DEV float4 b4f(ushort4 u) {
    return make_float4(b2f(u.x), b2f(u.y), b2f(u.z), b2f(u.w));
}
DEV unsigned short f2b(float f) {  // round-to-nearest-even
    union { float f; unsigned int i; } c; c.f = f;
    unsigned int lsb = (c.i >> 16) & 1u;
    c.i += 0x7fffu + lsb;
    return (unsigned short)(c.i >> 16);
}
// p = exp(-softplus(a)) = 1/(1+e^a);  dt = -log(p) = softplus(a)
DEV void dt_p_(float a, float& dt, float& p) {
    p = __builtin_amdgcn_rcpf(1.0f + __expf(a));
    dt = -__logf(p);
}
DEV void gload_lds16(const unsigned short* g, unsigned short* l) {
    __builtin_amdgcn_global_load_lds(
        (__attribute__((address_space(1))) void*)(g),
        (__attribute__((address_space(3))) void*)(l), 16, 0, 0);
}

// --------------- merged weight prep: WbI | WbO | WbX(pad) | cwT in one launch
__global__ void k_prep(const float* __restrict__ inproj_w, const float* __restrict__ outproj_w,
                       const float* __restrict__ xproj_w, const float* __restrict__ conv_w,
                       unsigned short* __restrict__ WbI, unsigned short* __restrict__ WbO,
                       unsigned short* __restrict__ WbX, float* __restrict__ cwT) {
    int idx = blockIdx.x * 256 + threadIdx.x;
    if (idx < PREP_T1) {
        int g = idx * 4;
        float4 v = *(const float4*)(inproj_w + g);
        ushort4 o; o.x = f2b(v.x); o.y = f2b(v.y); o.z = f2b(v.z); o.w = f2b(v.w);
        *(ushort4*)(WbI + g) = o;
        return;
    }
    if (idx < PREP_T2) {
        int g = (idx - PREP_T1) * 4;
        float4 v = *(const float4*)(outproj_w + g);
        ushort4 o; o.x = f2b(v.x); o.y = f2b(v.y); o.z = f2b(v.z); o.w = f2b(v.w);
        *(ushort4*)(WbO + g) = o;
        return;
    }
    if (idx < PREP_T3) {
        int q = idx - PREP_T2;                 // 2*48*512
        int l = q / (48 * 512), r = (q >> 9) % 48, cc = q & 511;
        WbX[q] = (r < 33) ? f2b(xproj_w[(size_t)(l * 33 + r) * 512 + cc]) : (unsigned short)0;
        return;
    }
    if (idx < PREP_T4) {
        int q = idx - PREP_T3;                 // 2*4*512
        int l = q >> 11, k = (q >> 9) & 3, d = q & 511;
        cwT[q] = conv_w[(size_t)(l * DI + d) * 4 + k];
    }
}

// ----------------- input proj + fused layer-0 LN (block = one token)
__global__ __launch_bounds__(256) void k_inproj(
    const float* __restrict__ z, const float* __restrict__ w,
    const float* __restrict__ bias, const float* __restrict__ gam,
    const float* __restrict__ bet, float* __restrict__ x,
    unsigned short* __restrict__ xln) {
    int i = blockIdx.x, m = threadIdx.x;
    int lane = m & 63, wid = m >> 6;
    float4 zv = *(const float4*)(z + (size_t)i * 4);
    float4 wv = *(const float4*)(w + (size_t)m * 4);
    float r = bias[m];
    r = fmaf(zv.x, wv.x, r);
    r = fmaf(zv.y, wv.y, r);
    r = fmaf(zv.z, wv.z, r);
    r = fmaf(zv.w, wv.w, r);
    x[(size_t)i * DM + m] = r;
    // block LN over 256 channels
    __shared__ float red[8];
    float s = r, q = r * r;
    #pragma unroll
    for (int k = 32; k; k >>= 1) { s += __shfl_xor(s, k, 64); q += __shfl_xor(q, k, 64); }
    if (lane == 0) { red[wid] = s; red[4 + wid] = q; }
    __syncthreads();
    float st = red[0] + red[1] + red[2] + red[3];
    float qt = red[4] + red[5] + red[6] + red[7];
    float mu = st * (1.0f / DM);
    float rs = rsqrtf(qt * (1.0f / DM) - mu * mu + EPSF);
    xln[(size_t)i * DM + m] = f2b((r - mu) * rs * gam[m] + bet[m]);
}

// -------------------------------------------- fused row-LN -> bf16 (per wave)
__global__ void k_lnrow(const float* __restrict__ x, const float* __restrict__ gam,
                        const float* __restrict__ bet, unsigned short* __restrict__ xln) {
    int lane = threadIdx.x & 63, wid = threadIdx.x >> 6;
    int i = blockIdx.x * 4 + wid;
    float4 v = *(const float4*)(x + (size_t)i * DM + lane * 4);
    float s = v.x + v.y + v.z + v.w;
    float q = v.x * v.x + v.y * v.y + v.z * v.z + v.w * v.w;
    #pragma unroll
    for (int m = 32; m; m >>= 1) { s += __shfl_xor(s, m, 64); q += __shfl_xor(q, m, 64); }
    float mu = s * (1.0f / DM);
    float rs = rsqrtf(q * (1.0f / DM) - mu * mu + EPSF);
    float4 g4 = *(const float4*)(gam + lane * 4);
    float4 b4 = *(const float4*)(bet + lane * 4);
    ushort4 o;
    o.x = f2b((v.x - mu) * rs * g4.x + b4.x);
    o.y = f2b((v.y - mu) * rs * g4.y + b4.y);
    o.z = f2b((v.z - mu) * rs * g4.z + b4.z);
    o.w = f2b((v.w - mu) * rs * g4.w + b4.w);
    *(ushort4*)(xln + (size_t)i * DM + lane * 4) = o;
}

// ------------------------------------- GEMM1 (MFMA): [xp|z] = xln @ WbI^T
__global__ __launch_bounds__(256) void k_gemm1(
    const unsigned short* __restrict__ A, const unsigned short* __restrict__ W,
    unsigned short* __restrict__ xpb, unsigned short* __restrict__ zbb) {
    __shared__ unsigned short As[128 * 32];
    __shared__ unsigned short Bs[128 * 32];
    int tid = threadIdx.x, lane = tid & 63, wid = tid >> 6;
    int tileN = blockIdx.x & 7, tileM = blockIdx.x >> 3;
    int i0 = tileM * 128, n0 = tileN * 128;
    f32x4 acc[4][4];
    #pragma unroll
    for (int mi = 0; mi < 4; mi++)
        #pragma unroll
        for (int ni = 0; ni < 4; ni++) acc[mi][ni] = (f32x4){0.f, 0.f, 0.f, 0.f};

    int srow = (wid << 5) + (lane >> 2);
    int sblk = lane & 3;
    const unsigned short* ga = A + (size_t)(i0 + srow) * 256 + sblk * 8;
    const unsigned short* gb = W + (size_t)(n0 + srow) * 256 + sblk * 8;
    unsigned short* la = As + (wid << 5) * 32;
    unsigned short* lb = Bs + (wid << 5) * 32;
    int ar = lane & 15, ab = lane >> 4;
    const short8* pa = (const short8*)(As + ((wid >> 1) * 64 + ar) * 32 + ab * 8);
    const short8* pb = (const short8*)(Bs + ((wid & 1) * 64 + ar) * 32 + ab * 8);

    for (int k0 = 0; k0 < 256; k0 += 32) {
        gload_lds16(ga + k0,            la);
        gload_lds16(ga + k0 + 16 * 256, la + 16 * 32);
        gload_lds16(gb + k0,            lb);
        gload_lds16(gb + k0 + 16 * 256, lb + 16 * 32);
        __syncthreads();
        short8 a[4], b[4];
        #pragma unroll
        for (int mi = 0; mi < 4; mi++) a[mi] = pa[mi * 64];
        #pragma unroll
        for (int ni = 0; ni < 4; ni++) b[ni] = pb[ni * 64];
        #pragma unroll
        for (int mi = 0; mi < 4; mi++)
            #pragma unroll
            for (int ni = 0; ni < 4; ni++)
                acc[mi][ni] = __builtin_amdgcn_mfma_f32_16x16x32_bf16(a[mi], b[ni], acc[mi][ni], 0, 0, 0);
        __syncthreads();
    }
    int wr = wid >> 1, wc = wid & 1;
    int rbase = i0 + wr * 64 + (lane >> 4) * 4;
    int cbase = n0 + wc * 64 + (lane & 15);
    unsigned short* dst = (n0 < 512) ? xpb : zbb;
    int coff = (n0 < 512) ? cbase : cbase - 512;
    #pragma unroll
    for (int mi = 0; mi < 4; mi++)
        #pragma unroll
        for (int ni = 0; ni < 4; ni++)
            #pragma unroll
            for (int j = 0; j < 4; j++)
                dst[(size_t)(rbase + mi * 16 + j) * 512 + coff + ni * 16] = f2b(acc[mi][ni][j]);
}

// ---------------- depthwise causal conv + SiLU -> bf16 (rolling window, 8 tok/thread)
__global__ void k_conv(const unsigned short* __restrict__ xpb, const float* __restrict__ cwT,
                       const float* __restrict__ cb, unsigned short* __restrict__ xcb) {
    int g = blockIdx.x * 256 + threadIdx.x;     // NTOK/8 * 128 threads
    int tg = g >> 7, dq = g & 127;
    int d = dq * 4;
    int i0 = tg * 8;
    float4 w0 = *(const float4*)(cwT + 0 * DI + d);
    float4 w1 = *(const float4*)(cwT + 1 * DI + d);
    float4 w2 = *(const float4*)(cwT + 2 * DI + d);
    float4 w3 = *(const float4*)(cwT + 3 * DI + d);
    float4 bi = *(const float4*)(cb + d);
    float4 x0, x1, x2;
    if ((i0 & (SEQL - 1)) != 0) {
        x0 = b4f(*(const ushort4*)(xpb + (size_t)(i0 - 3) * DI + d));
        x1 = b4f(*(const ushort4*)(xpb + (size_t)(i0 - 2) * DI + d));
        x2 = b4f(*(const ushort4*)(xpb + (size_t)(i0 - 1) * DI + d));
    } else {
        x0 = x1 = x2 = make_float4(0.f, 0.f, 0.f, 0.f);
    }
    #pragma unroll
    for (int tt = 0; tt < 8; tt++) {
        float4 xc = b4f(*(const ushort4*)(xpb + (size_t)(i0 + tt) * DI + d));
        float4 a = bi;
        a.x = fmaf(w0.x, x0.x, a.x); a.y = fmaf(w0.y, x0.y, a.y);
        a.z = fmaf(w0.z, x0.z, a.z); a.w = fmaf(w0.w, x0.w, a.w);
        a.x = fmaf(w1.x, x1.x, a.x); a.y = fmaf(w1.y, x1.y, a.y);
        a.z = fmaf(w1.z, x1.z, a.z); a.w = fmaf(w1.w, x1.w, a.w);
        a.x = fmaf(w2.x, x2.x, a.x); a.y = fmaf(w2.y, x2.y, a.y);
        a.z = fmaf(w2.z, x2.z, a.z); a.w = fmaf(w2.w, x2.w, a.w);
        a.x = fmaf(w3.x, xc.x, a.x); a.y = fmaf(w3.y, xc.y, a.y);
        a.z = fmaf(w3.z, xc.z, a.z); a.w = fmaf(w3.w, xc.w, a.w);
        ushort4 o;
        o.x = f2b(siluf_(a.x)); o.y = f2b(siluf_(a.y));
        o.z = f2b(siluf_(a.z)); o.w = f2b(siluf_(a.w));
        *(ushort4*)(xcb + (size_t)(i0 + tt) * DI + d) = o;
        x0 = x1; x1 = x2; x2 = xc;
    }
}

// --------------------- xproj (MFMA): ssm = xcb @ WX_pad^T (N=48, rows>=33 dead)
__global__ __launch_bounds__(256) void k_xprojm(
    const unsigned short* __restrict__ A, const unsigned short* __restrict__ W,
    float* __restrict__ Bm, float* __restrict__ Cm, float* __restrict__ dtr) {
    __shared__ unsigned short As[128 * 32];
    __shared__ unsigned short Bs[48 * 32];
    int tid = threadIdx.x, lane = tid & 63, wid = tid >> 6;
    int i0 = blockIdx.x * 128;
    f32x4 acc[2][3];
    #pragma unroll
    for (int mi = 0; mi < 2; mi++)
        #pragma unroll
        for (int ni = 0; ni < 3; ni++) acc[mi][ni] = (f32x4){0.f, 0.f, 0.f, 0.f};

    int srow = lane >> 2, sblk = lane & 3;
    const unsigned short* ga = A + (size_t)(i0 + (wid << 5) + srow) * 512 + sblk * 8;
    unsigned short* la = As + (wid << 5) * 32;
    const unsigned short* gb = W + (size_t)((wid << 4) + srow) * 512 + sblk * 8;
    unsigned short* lb = Bs + (wid << 4) * 32;
    int ar = lane & 15, ab = lane >> 4;

    for (int k0 = 0; k0 < 512; k0 += 32) {
        gload_lds16(ga + k0,            la);
        gload_lds16(ga + k0 + 16 * 512, la + 16 * 32);
        if (wid < 3) gload_lds16(gb + k0, lb);
        __syncthreads();
        short8 a[2], b[3];
        #pragma unroll
        for (int mi = 0; mi < 2; mi++)
            a[mi] = *(const short8*)(As + ((wid << 5) + mi * 16 + ar) * 32 + ab * 8);
        #pragma unroll
        for (int ni = 0; ni < 3; ni++)
            b[ni] = *(const short8*)(Bs + (ni * 16 + ar) * 32 + ab * 8);
        #pragma unroll
        for (int mi = 0; mi < 2; mi++)
            #pragma unroll
            for (int ni = 0; ni < 3; ni++)
                acc[mi][ni] = __builtin_amdgcn_mfma_f32_16x16x32_bf16(a[mi], b[ni], acc[mi][ni], 0, 0, 0);
        __syncthreads();
    }
    #pragma unroll
    for (int mi = 0; mi < 2; mi++)
        #pragma unroll
        for (int ni = 0; ni < 3; ni++)
            #pragma unroll
            for (int j = 0; j < 4; j++) {
                int row = i0 + (wid << 5) + mi * 16 + (lane >> 4) * 4 + j;
                int ng = ni * 16 + (lane & 15);
                float v = acc[mi][ni][j];
                if (ng < 16)       Bm[(size_t)row * DS + ng] = v;
                else if (ng < 32)  Cm[(size_t)row * DS + ng - 16] = v;
                else if (ng == 32) dtr[row] = v;
            }
}

// ---- scan phase 1: 2 channels/thread, named float4 regs, x staged in LDS
__global__ __launch_bounds__(128, 2) void k_scan1(
    const unsigned short* __restrict__ xcb, const float* __restrict__ Bm,
    const float* __restrict__ dtr, const float* __restrict__ dw,
    const float* __restrict__ db, float* __restrict__ hend, float* __restrict__ dtc) {
    __shared__ unsigned short Xsh[TC][256];     // 16 KB
    __shared__ float Bsh[TC][16];
    __shared__ float dtl[TC];
    int tid = threadIdx.x;                      // 0..127
    int blk = blockIdx.x;                       // ((b*NCH)+c)*2 + half
    int half = blk & 1, c = (blk >> 1) & (NCH - 1), b = blk >> 8;
    int i0 = (b << 12) + c * TC;
    {   // async stage x: 2 waves, 8 calls each (2 rows per call, stride 4)
        int lane = tid & 63, wv = tid >> 6;
        const unsigned short* gsrc = xcb + (size_t)(i0 + wv * 2 + (lane >> 5)) * DI
                                   + half * 256 + (lane & 31) * 8;
        unsigned short* ldst = &Xsh[wv * 2][0];
        #pragma unroll
        for (int r = 0; r < 8; r++)
            gload_lds16(gsrc + (size_t)r * 4 * DI, ldst + r * 4 * 256);
    }
    if (tid < TC) dtl[tid] = dtr[i0 + tid];
    {
        int tt = tid >> 2, ss = (tid & 3) * 4;  // 128 threads = 128 float4s of B
        *(float4*)(&Bsh[tt][ss]) = *(const float4*)(Bm + (size_t)(i0 + tt) * DS + ss);
    }
    __syncthreads();
    int d0 = half * 256 + tid * 2;
    float2 dwd = *(const float2*)(dw + d0);
    float2 dbd = *(const float2*)(db + d0);
    float4 ha0 = make_float4(0.f,0.f,0.f,0.f), ha1 = ha0, ha2 = ha0, ha3 = ha0;
    float4 hb0 = ha0, hb1 = ha0, hb2 = ha0, hb3 = ha0;
    float dts0 = 0.0f, dts1 = 0.0f;
    for (int t = 0; t < TC; t++) {
        float dt0, p0, dt1, p1;
        dt_p_(fmaf(dtl[t], dwd.x, dbd.x), dt0, p0);
        dt_p_(fmaf(dtl[t], dwd.y, dbd.y), dt1, p1);
        dts0 += dt0; dts1 += dt1;
        ushort2 xv = *(const ushort2*)(&Xsh[t][tid * 2]);
        float dtx0 = dt0 * b2f(xv.x);
        float dtx1 = dt1 * b2f(xv.y);
        float4 B0 = *(const float4*)(&Bsh[t][0]);
        float4 B1 = *(const float4*)(&Bsh[t][4]);
        float4 B2 = *(const float4*)(&Bsh[t][8]);
        float4 B3 = *(const float4*)(&Bsh[t][12]);
        float q2 = p0*p0, q3 = q2*p0, q4 = q2*q2, q5 = q4*p0, q6 = q4*q2, q7 = q4*q3, q8 = q4*q4;
        float q9 = q8*p0, q10 = q8*q2, q11 = q8*q3, q12 = q8*q4, q13 = q8*q5, q14 = q8*q6, q15 = q8*q7, q16 = q8*q8;
        ha0.x = fmaf(p0,  ha0.x, dtx0 * B0.x); ha0.y = fmaf(q2,  ha0.y, dtx0 * B0.y);
        ha0.z = fmaf(q3,  ha0.z, dtx0 * B0.z); ha0.w = fmaf(q4,  ha0.w, dtx0 * B0.w);
        ha1.x = fmaf(q5,  ha1.x, dtx0 * B1.x); ha1.y = fmaf(q6,  ha1.y, dtx0 * B1.y);
        ha1.z = fmaf(q7,  ha1.z, dtx0 * B1.z); ha1.w = fmaf(q8,  ha1.w, dtx0 * B1.w);
        ha2.x = fmaf(q9,  ha2.x, dtx0 * B2.x); ha2.y = fmaf(q10, ha2.y, dtx0 * B2.y);
        ha2.z = fmaf(q11, ha2.z, dtx0 * B2.z); ha2.w = fmaf(q12, ha2.w, dtx0 * B2.w);
        ha3.x = fmaf(q13, ha3.x, dtx0 * B3.x); ha3.y = fmaf(q14, ha3.y, dtx0 * B3.y);
        ha3.z = fmaf(q15, ha3.z, dtx0 * B3.z); ha3.w = fmaf(q16, ha3.w, dtx0 * B3.w);
        float r2 = p1*p1, r3 = r2*p1, r4 = r2*r2, r5 = r4*p1, r6 = r4*r2, r7 = r4*r3, r8 = r4*r4;
        float r9 = r8*p1, r10 = r8*r2, r11 = r8*r3, r12 = r8*r4, r13 = r8*r5, r14 = r8*r6, r15 = r8*r7, r16 = r8*r8;
        hb0.x = fmaf(p1,  hb0.x, dtx1 * B0.x); hb0.y = fmaf(r2,  hb0.y, dtx1 * B0.y);
        hb0.z = fmaf(r3,  hb0.z, dtx1 * B0.z); hb0.w = fmaf(r4,  hb0.w, dtx1 * B0.w);
        hb1.x = fmaf(r5,  hb1.x, dtx1 * B1.x); hb1.y = fmaf(r6,  hb1.y, dtx1 * B1.y);
        hb1.z = fmaf(r7,  hb1.z, dtx1 * B1.z); hb1.w = fmaf(r8,  hb1.w, dtx1 * B1.w);
        hb2.x = fmaf(r9,  hb2.x, dtx1 * B2.x); hb2.y = fmaf(r10, hb2.y, dtx1 * B2.y);
        hb2.z = fmaf(r11, hb2.z, dtx1 * B2.z); hb2.w = fmaf(r12, hb2.w, dtx1 * B2.w);
        hb3.x = fmaf(r13, hb3.x, dtx1 * B3.x); hb3.y = fmaf(r14, hb3.y, dtx1 * B3.y);
        hb3.z = fmaf(r15, hb3.z, dtx1 * B3.z); hb3.w = fmaf(r16, hb3.w, dtx1 * B3.w);
    }
    size_t hb_ = ((size_t)(b * DI + d0) * NCH + c) * DS;
    *(float4*)(hend + hb_ + 0)  = ha0;
    *(float4*)(hend + hb_ + 4)  = ha1;
    *(float4*)(hend + hb_ + 8)  = ha2;
    *(float4*)(hend + hb_ + 12) = ha3;
    size_t hb2_ = hb_ + (size_t)NCH * DS;
    *(float4*)(hend + hb2_ + 0)  = hb0;
    *(float4*)(hend + hb2_ + 4)  = hb1;
    *(float4*)(hend + hb2_ + 8)  = hb2;
    *(float4*)(hend + hb2_ + 12) = hb3;
    dtc[(size_t)(b * DI + d0) * NCH + c] = dts0;
    dtc[(size_t)(b * DI + d0 + 1) * NCH + c] = dts1;
}

// ------------- scan phase 2: propagate chunk-entry states; thread per (b,d,s)
__global__ void k_scan2(float* __restrict__ hend, const float* __restrict__ dtc) {
    int g = blockIdx.x * 256 + threadIdx.x;     // BATCH*DI*DS = 65536
    int s = g & 15, dd = (g >> 4) & 511, b = g >> 13;
    size_t base = (size_t)(b * DI + dd) * NCH;
    float hin = 0.0f;
    float kneg = -(float)(s + 1);
    #pragma unroll 4
    for (int c = 0; c < NCH; c++) {
        size_t a = (base + c) * DS + s;
        float tmp = hend[a];
        float pb = __expf(kneg * dtc[base + c]);
        hend[a] = hin;
        hin = fmaf(pb, hin, tmp);
    }
}

// ---- scan phase 3: 2 channels/thread, named float4 regs; x,z staged in LDS
__global__ __launch_bounds__(128, 2) void k_scan3(
    const unsigned short* __restrict__ xcb, const float* __restrict__ Bm,
    const float* __restrict__ Cm, const float* __restrict__ dtr,
    const float* __restrict__ dw, const float* __restrict__ db,
    const float* __restrict__ hend, const unsigned short* __restrict__ zbb,
    unsigned short* __restrict__ ygb) {
    __shared__ unsigned short Xsh[TC][256];     // 16 KB
    __shared__ unsigned short Zsh[TC][256];     // 16 KB
    __shared__ float Bsh[TC][16];
    __shared__ float Csh[TC][16];
    __shared__ float dtl[TC];
    int tid = threadIdx.x;                      // 0..127
    int blk = blockIdx.x;
    int half = blk & 1, c = (blk >> 1) & (NCH - 1), b = blk >> 8;
    int i0 = (b << 12) + c * TC;
    {   // async stage x and z chunks: 2 waves, 8 calls each
        int lane = tid & 63, wv = tid >> 6;
        size_t goff = (size_t)(i0 + wv * 2 + (lane >> 5)) * DI + half * 256 + (lane & 31) * 8;
        const unsigned short* gx = xcb + goff;
        const unsigned short* gz = zbb + goff;
        unsigned short* lx = &Xsh[wv * 2][0];
        unsigned short* lz = &Zsh[wv * 2][0];
        #pragma unroll
        for (int r = 0; r < 8; r++) {
            gload_lds16(gx + (size_t)r * 4 * DI, lx + r * 4 * 256);
            gload_lds16(gz + (size_t)r * 4 * DI, lz + r * 4 * 256);
        }
    }
    if (tid < TC) dtl[tid] = dtr[i0 + tid];
    {
        int tt = tid >> 2, ss = (tid & 3) * 4;
        *(float4*)(&Bsh[tt][ss]) = *(const float4*)(Bm + (size_t)(i0 + tt) * DS + ss);
        *(float4*)(&Csh[tt][ss]) = *(const float4*)(Cm + (size_t)(i0 + tt) * DS + ss);
    }
    __syncthreads();
    int d0 = half * 256 + tid * 2;
    float2 dwd = *(const float2*)(dw + d0);
    float2 dbd = *(const float2*)(db + d0);
    size_t hb_ = ((size_t)(b * DI + d0) * NCH + c) * DS;
    float4 ha0 = *(const float4*)(hend + hb_ + 0);
    float4 ha1 = *(const float4*)(hend + hb_ + 4);
    float4 ha2 = *(const float4*)(hend + hb_ + 8);
    float4 ha3 = *(const float4*)(hend + hb_ + 12);
    size_t hb2_ = hb_ + (size_t)NCH * DS;
    float4 hb0 = *(const float4*)(hend + hb2_ + 0);
    float4 hb1 = *(const float4*)(hend + hb2_ + 4);
    float4 hb2 = *(const float4*)(hend + hb2_ + 8);
    float4 hb3 = *(const float4*)(hend + hb2_ + 12);
    unsigned short* yp = ygb + (size_t)i0 * DI + d0;
    for (int t = 0; t < TC; t++) {
        float dt0, p0, dt1, p1;
        dt_p_(fmaf(dtl[t], dwd.x, dbd.x), dt0, p0);
        dt_p_(fmaf(dtl[t], dwd.y, dbd.y), dt1, p1);
        ushort2 xv = *(const ushort2*)(&Xsh[t][tid * 2]);
        float dtx0 = dt0 * b2f(xv.x);
        float dtx1 = dt1 * b2f(xv.y);
        float4 B0 = *(const float4*)(&Bsh[t][0]);
        float4 B1 = *(const float4*)(&Bsh[t][4]);
        float4 B2 = *(const float4*)(&Bsh[t][8]);
        float4 B3 = *(const float4*)(&Bsh[t][12]);
        float4 C0 = *(const float4*)(&Csh[t][0]);
        float4 C1 = *(const float4*)(&Csh[t][4]);
        float4 C2 = *(const float4*)(&Csh[t][8]);
        float4 C3 = *(const float4*)(&Csh[t][12]);
        float q2 = p0*p0, q3 = q2*p0, q4 = q2*q2, q5 = q4*p0, q6 = q4*q2, q7 = q4*q3, q8 = q4*q4;
        float q9 = q8*p0, q10 = q8*q2, q11 = q8*q3, q12 = q8*q4, q13 = q8*q5, q14 = q8*q6, q15 = q8*q7, q16 = q8*q8;
        ha0.x = fmaf(p0,  ha0.x, dtx0 * B0.x); ha0.y = fmaf(q2,  ha0.y, dtx0 * B0.y);
        ha0.z = fmaf(q3,  ha0.z, dtx0 * B0.z); ha0.w = fmaf(q4,  ha0.w, dtx0 * B0.w);
        ha1.x = fmaf(q5,  ha1.x, dtx0 * B1.x); ha1.y = fmaf(q6,  ha1.y, dtx0 * B1.y);
        ha1.z = fmaf(q7,  ha1.z, dtx0 * B1.z); ha1.w = fmaf(q8,  ha1.w, dtx0 * B1.w);
        ha2.x = fmaf(q9,  ha2.x, dtx0 * B2.x); ha2.y = fmaf(q10, ha2.y, dtx0 * B2.y);
        ha2.z = fmaf(q11, ha2.z, dtx0 * B2.z); ha2.w = fmaf(q12, ha2.w, dtx0 * B2.w);
        ha3.x = fmaf(q13, ha3.x, dtx0 * B3.x); ha3.y = fmaf(q14, ha3.y, dtx0 * B3.y);
        ha3.z = fmaf(q15, ha3.z, dtx0 * B3.z); ha3.w = fmaf(q16, ha3.w, dtx0 * B3.w);
        float y0 = 0.0f;
        y0 = fmaf(ha0.x, C0.x, y0); y0 = fmaf(ha0.y, C0.y, y0);
        y0 = fmaf(ha0.z, C0.z, y0); y0 = fmaf(ha0.w, C0.w, y0);
        y0 = fmaf(ha1.x, C1.x, y0); y0 = fmaf(ha1.y, C1.y, y0);
        y0 = fmaf(ha1.z, C1.z, y0); y0 = fmaf(ha1.w, C1.w, y0);
        y0 = fmaf(ha2.x, C2.x, y0); y0 = fmaf(ha2.y, C2.y, y0);
        y0 = fmaf(ha2.z, C2.z, y0); y0 = fmaf(ha2.w, C2.w, y0);
        y0 = fmaf(ha3.x, C3.x, y0); y0 = fmaf(ha3.y, C3.y, y0);
        y0 = fmaf(ha3.z, C3.z, y0); y0 = fmaf(ha3.w, C3.w, y0);
        float r2 = p1*p1, r3 = r2*p1, r4 = r2*r2, r5 = r4*p1, r6 = r4*r2, r7 = r4*r3, r8 = r4*r4;
        float r9 = r8*p1, r10 = r8*r2, r11 = r8*r3, r12 = r8*r4, r13 = r8*r5, r14 = r8*r6, r15 = r8*r7, r16 = r8*r8;
        hb0.x = fmaf(p1,  hb0.x, dtx1 * B0.x); hb0.y = fmaf(r2,  hb0.y, dtx1 * B0.y);
        hb0.z = fmaf(r3,  hb0.z, dtx1 * B0.z); hb0.w = fmaf(r4,  hb0.w, dtx1 * B0.w);
        hb1.x = fmaf(r5,  hb1.x, dtx1 * B1.x); hb1.y = fmaf(r6,  hb1.y, dtx1 * B1.y);
        hb1.z = fmaf(r7,  hb1.z, dtx1 * B1.z); hb1.w = fmaf(r8,  hb1.w, dtx1 * B1.w);
        hb2.x = fmaf(r9,  hb2.x, dtx1 * B2.x); hb2.y = fmaf(r10, hb2.y, dtx1 * B2.y);
        hb2.z = fmaf(r11, hb2.z, dtx1 * B2.z); hb2.w = fmaf(r12, hb2.w, dtx1 * B2.w);
        hb3.x = fmaf(r13, hb3.x, dtx1 * B3.x); hb3.y = fmaf(r14, hb3.y, dtx1 * B3.y);
        hb3.z = fmaf(r15, hb3.z, dtx1 * B3.z); hb3.w = fmaf(r16, hb3.w, dtx1 * B3.w);
        float y1 = 0.0f;
        y1 = fmaf(hb0.x, C0.x, y1); y1 = fmaf(hb0.y, C0.y, y1);
        y1 = fmaf(hb0.z, C0.z, y1); y1 = fmaf(hb0.w, C0.w, y1);
        y1 = fmaf(hb1.x, C1.x, y1); y1 = fmaf(hb1.y, C1.y, y1);
        y1 = fmaf(hb1.z, C1.z, y1); y1 = fmaf(hb1.w, C1.w, y1);
        y1 = fmaf(hb2.x, C2.x, y1); y1 = fmaf(hb2.y, C2.y, y1);
        y1 = fmaf(hb2.z, C2.z, y1); y1 = fmaf(hb2.w, C2.w, y1);
        y1 = fmaf(hb3.x, C3.x, y1); y1 = fmaf(hb3.y, C3.y, y1);
        y1 = fmaf(hb3.z, C3.z, y1); y1 = fmaf(hb3.w, C3.w, y1);
        ushort2 zv = *(const ushort2*)(&Zsh[t][tid * 2]);
        ushort2 o;
        o.x = f2b(y0 * siluf_(b2f(zv.x)));
        o.y = f2b(y1 * siluf_(b2f(zv.y)));
        *(ushort2*)(yp + (size_t)t * DI) = o;
    }
}

// ----------------------- outproj (MFMA): x += ygb @ WbO^T  (residual add)
__global__ __launch_bounds__(256) void k_outproj(
    const unsigned short* __restrict__ A, const unsigned short* __restrict__ W,
    float* __restrict__ x) {
    __shared__ unsigned short As[128 * 32];
    __shared__ unsigned short Bs[128 * 32];
    int tid = threadIdx.x, lane = tid & 63, wid = tid >> 6;
    int tileN = blockIdx.x & 1, tileM = blockIdx.x >> 1;
    int i0 = tileM * 128, n0 = tileN * 128;
    f32x4 acc[4][4];
    #pragma unroll
    for (int mi = 0; mi < 4; mi++)
        #pragma unroll
        for (int ni = 0; ni < 4; ni++) acc[mi][ni] = (f32x4){0.f, 0.f, 0.f, 0.f};

    int srow = (wid << 5) + (lane >> 2);
    int sblk = lane & 3;
    const unsigned short* ga = A + (size_t)(i0 + srow) * 512 + sblk * 8;
    const unsigned short* gb = W + (size_t)(n0 + srow) * 512 + sblk * 8;
    unsigned short* la = As + (wid << 5) * 32;
    unsigned short* lb = Bs + (wid << 5) * 32;
    int ar = lane & 15, ab = lane >> 4;
    const short8* pa = (const short8*)(As + ((wid >> 1) * 64 + ar) * 32 + ab * 8);
    const short8* pb = (const short8*)(Bs + ((wid & 1) * 64 + ar) * 32 + ab * 8);

    for (int k0 = 0; k0 < 512; k0 += 32) {
        gload_lds16(ga + k0,            la);
        gload_lds16(ga + k0 + 16 * 512, la + 16 * 32);
        gload_lds16(gb + k0,            lb);
        gload_lds16(gb + k0 + 16 * 512, lb + 16 * 32);
        __syncthreads();
        short8 a[4], b[4];
        #pragma unroll
        for (int mi = 0; mi < 4; mi++) a[mi] = pa[mi * 64];
        #pragma unroll
        for (int ni = 0; ni < 4; ni++) b[ni] = pb[ni * 64];
        #pragma unroll
        for (int mi = 0; mi < 4; mi++)
            #pragma unroll
            for (int ni = 0; ni < 4; ni++)
                acc[mi][ni] = __builtin_amdgcn_mfma_f32_16x16x32_bf16(a[mi], b[ni], acc[mi][ni], 0, 0, 0);
        __syncthreads();
    }
    int wr = wid >> 1, wc = wid & 1;
    int rbase = i0 + wr * 64 + (lane >> 4) * 4;
    int cbase = n0 + wc * 64 + (lane & 15);
    #pragma unroll
    for (int mi = 0; mi < 4; mi++)
        #pragma unroll
        for (int ni = 0; ni < 4; ni++)
            #pragma unroll
            for (int j = 0; j < 4; j++) {
                size_t idx = (size_t)(rbase + mi * 16 + j) * DM + cbase + ni * 16;
                x[idx] += acc[mi][ni][j];
            }
}

// -------------------------------------------- final LN + output projection
__global__ void k_final(const float* __restrict__ x, const float* __restrict__ gam,
                        const float* __restrict__ bet, const float* __restrict__ w,
                        const float* __restrict__ bias, float* __restrict__ out) {
    int lane = threadIdx.x & 63, wid = threadIdx.x >> 6;
    int i = blockIdx.x * 4 + wid;
    float4 v = *(const float4*)(x + (size_t)i * DM + lane * 4);
    float s = v.x + v.y + v.z + v.w;
    float q = v.x * v.x + v.y * v.y + v.z * v.z + v.w * v.w;
    #pragma unroll
    for (int m = 32; m; m >>= 1) { s += __shfl_xor(s, m, 64); q += __shfl_xor(q, m, 64); }
    float mu = s * (1.0f / DM);
    float rs = rsqrtf(q * (1.0f / DM) - mu * mu + EPSF);
    float4 gg = *(const float4*)(gam + lane * 4);
    float4 bb = *(const float4*)(bet + lane * 4);
    float xn[4] = {(v.x - mu) * rs * gg.x + bb.x, (v.y - mu) * rs * gg.y + bb.y,
                   (v.z - mu) * rs * gg.z + bb.z, (v.w - mu) * rs * gg.w + bb.w};
    float4 w0 = *(const float4*)(w + lane * 4);
    float4 w1 = *(const float4*)(w + DM + lane * 4);
    float p0 = xn[0] * w0.x + xn[1] * w0.y + xn[2] * w0.z + xn[3] * w0.w;
    float p1 = xn[0] * w1.x + xn[1] * w1.y + xn[2] * w1.z + xn[3] * w1.w;
    #pragma unroll
    for (int m = 32; m; m >>= 1) { p0 += __shfl_xor(p0, m, 64); p1 += __shfl_xor(p1, m, 64); }
    if (lane == 0) {
        out[(size_t)i * 2]     = p0 + bias[0];
        out[(size_t)i * 2 + 1] = p1 + bias[1];
    }
}

// ---------------------------------------------------------------------------
extern "C" void kernel_launch(void* const* d_in, const int* in_sizes, int n_in,
                              void* d_out, int out_size, void* d_ws, size_t ws_size,
                              hipStream_t stream) {
    const float* z_seq     = (const float*)d_in[0];
    const float* ip_w      = (const float*)d_in[1];
    const float* ip_b      = (const float*)d_in[2];
    const float* norm_g    = (const float*)d_in[3];
    const float* norm_b    = (const float*)d_in[4];
    const float* inproj_w  = (const float*)d_in[5];
    const float* conv_w    = (const float*)d_in[6];
    const float* conv_b    = (const float*)d_in[7];
    const float* xproj_w   = (const float*)d_in[8];
    const float* dt_w      = (const float*)d_in[9];
    const float* dt_b      = (const float*)d_in[10];
    const float* outproj_w = (const float*)d_in[11];
    const float* onorm_g   = (const float*)d_in[12];
    const float* onorm_b   = (const float*)d_in[13];
    const float* op_w      = (const float*)d_in[14];
    const float* op_b      = (const float*)d_in[15];

    char* ws = (char*)d_ws;
    float* x    = (float*)(ws + OFF_X);
    unsigned short* xpb = (unsigned short*)(ws + OFF_XPB);
    unsigned short* zbb = (unsigned short*)(ws + OFF_ZBB);
    unsigned short* xcb = (unsigned short*)(ws + OFF_XCB);
    unsigned short* xln = (unsigned short*)(ws + OFF_XLN);
    float* Bmb  = (float*)(ws + OFF_B);
    float* Cmb  = (float*)(ws + OFF_C);
    float* dtrb = (float*)(ws + OFF_DTR);
    float* hend = (float*)(ws + OFF_HE);
    float* dtc  = (float*)(ws + OFF_DTC);
    unsigned short* WbI = (unsigned short*)(ws + OFF_WBI);
    unsigned short* WbO = (unsigned short*)(ws + OFF_WBO);
    unsigned short* WbX = (unsigned short*)(ws + OFF_WBX);
    float* cwT  = (float*)(ws + OFF_CWT);

    k_prep<<<PREP_T4 / 256, 256, 0, stream>>>(inproj_w, outproj_w, xproj_w, conv_w,
                                              WbI, WbO, WbX, cwT);
    // inproj + fused layer-0 LN
    k_inproj<<<NTOK, 256, 0, stream>>>(z_seq, ip_w, ip_b, norm_g, norm_b, x, xln);

    for (int l = 0; l < 2; l++) {
        if (l > 0)
            k_lnrow<<<NTOK / 4, 256, 0, stream>>>(x, norm_g + l * DM, norm_b + l * DM, xln);
        k_gemm1<<<(NTOK / 128) * 8, 256, 0, stream>>>(
            xln, WbI + (size_t)l * 2 * DI * DM, xpb, zbb);
        k_conv<<<(NTOK / 8) * 128 / 256, 256, 0, stream>>>(
            xpb, cwT + (size_t)l * 4 * DI, conv_b + (size_t)l * DI, xcb);
        k_xprojm<<<NTOK / 128, 256, 0, stream>>>(
            xcb, WbX + (size_t)l * 48 * DI, Bmb, Cmb, dtrb);
        k_scan1<<<BATCH * NCH * 2, 128, 0, stream>>>(
            xcb, Bmb, dtrb, dt_w + l * DI, dt_b + l * DI, hend, dtc);
        k_scan2<<<BATCH * DI * DS / 256, 256, 0, stream>>>(hend, dtc);
        k_scan3<<<BATCH * NCH * 2, 128, 0, stream>>>(
            xcb, Bmb, Cmb, dtrb, dt_w + l * DI, dt_b + l * DI, hend, zbb, xpb);
        k_outproj<<<(NTOK / 128) * 2, 256, 0, stream>>>(
            xpb, WbO + (size_t)l * DM * DI, x);
    }
    k_final<<<NTOK / 4, 256, 0, stream>>>(x, onorm_g, onorm_b, op_w, op_b, (float*)d_out);
}

// Round 16
// 495.819 us; speedup vs baseline: 1.0821x; 1.0821x over previous
//
#include <hip/hip_runtime.h>
#include <cstddef>
#include <cstdint>

#define DEV __device__ __forceinline__

namespace {
constexpr int BATCH = 8;
constexpr int SEQL  = 4096;
constexpr int DM    = 256;   // d_model
constexpr int DS    = 16;    // d_state
constexpr int DI    = 512;   // d_inner
constexpr int NTOK  = BATCH * SEQL;   // 32768
constexpr int TC    = 32;             // scan chunk length
constexpr int NCH   = SEQL / TC;      // 128 chunks per sequence
constexpr float EPSF = 1e-5f;

// workspace offsets (bytes)
constexpr size_t OFF_X   = 0;                                   // fp32 NTOK*DM
constexpr size_t OFF_XPB = OFF_X   + (size_t)NTOK * DM * 4;     // bf16 NTOK*DI (xp -> ygb)
constexpr size_t OFF_ZBB = OFF_XPB + (size_t)NTOK * DI * 2;     // bf16 NTOK*DI (z)
constexpr size_t OFF_XCB = OFF_ZBB + (size_t)NTOK * DI * 2;     // bf16 NTOK*DI (conv out)
constexpr size_t OFF_XLN = OFF_XCB + (size_t)NTOK * DI * 2;     // bf16 NTOK*DM
constexpr size_t OFF_B   = OFF_XLN + (size_t)NTOK * DM * 2;     // fp32 NTOK*DS
constexpr size_t OFF_C   = OFF_B   + (size_t)NTOK * DS * 4;     // fp32 NTOK*DS
constexpr size_t OFF_DTR = OFF_C   + (size_t)NTOK * DS * 4;     // fp32 NTOK
constexpr size_t OFF_HE  = OFF_DTR + (size_t)NTOK * 4;          // fp32 BATCH*DI*NCH*DS
constexpr size_t OFF_DTC = OFF_HE  + (size_t)BATCH * DI * NCH * DS * 4; // fp32 BATCH*DI*NCH
constexpr size_t OFF_WBI = OFF_DTC + (size_t)BATCH * DI * NCH * 4;      // bf16 2*1024*256
constexpr size_t OFF_WBO = OFF_WBI + (size_t)2 * 2 * DI * DM * 2;       // bf16 2*256*512
constexpr size_t OFF_WBX = OFF_WBO + (size_t)2 * DM * DI * 2;           // bf16 2*48*512 (padded)
constexpr size_t OFF_CWT = OFF_WBX + (size_t)2 * 48 * DI * 2;           // fp32 2*4*512 transposed conv w
constexpr size_t WBI_EL  = 2 * 2 * DI * DM;   // 524288
constexpr size_t WBO_EL  = 2 * DM * DI;       // 262144
constexpr int PREP_T1 = (int)(WBI_EL / 4);           // 131072
constexpr int PREP_T2 = PREP_T1 + (int)(WBO_EL / 4); // +65536
constexpr int PREP_T3 = PREP_T2 + 2 * 48 * 512;      // +49152
constexpr int PREP_T4 = PREP_T3 + 2 * 4 * 512;       // +4096 = 249856
} // namespace

typedef __attribute__((ext_vector_type(8))) short short8;
typedef __attribute__((ext_vector_type(4))) float f32x4;

DEV float sigmoidf_(float v) { return 1.0f / (1.0f + __expf(-v)); }
DEV float siluf_(float v)    { return v * sigmoidf_(v); }
DEV float b2f(unsigned short u) {
    union { unsigned int i; float f; } c; c.i = ((unsigned int)u) << 16; return c.f;
}
DEV float4 b4f(ushort4 u) {
    return make_float4(b2f(u.x), b2f(u.y), b2f(u.z), b2f(u.w));
}
DEV unsigned short f2b(float f) {  // round-to-nearest-even
    union { float f; unsigned int i; } c; c.f = f;
    unsigned int lsb = (c.i >> 16) & 1u;
    c.i += 0x7fffu + lsb;
    return (unsigned short)(c.i >> 16);
}
// p = exp(-softplus(a)) = 1/(1+e^a);  dt = -log(p) = softplus(a)
DEV void dt_p_(float a, float& dt, float& p) {
    p = __builtin_amdgcn_rcpf(1.0f + __expf(a));
    dt = -__logf(p);
}
DEV void gload_lds16(const unsigned short* g, unsigned short* l) {
    __builtin_amdgcn_global_load_lds(
        (__attribute__((address_space(1))) void*)(g),
        (__attribute__((address_space(3))) void*)(l), 16, 0, 0);
}

// --------------- merged weight prep: WbI | WbO | WbX(pad) | cwT in one launch
__global__ void k_prep(const float* __restrict__ inproj_w, const float* __restrict__ outproj_w,
                       const float* __restrict__ xproj_w, const float* __restrict__ conv_w,
                       unsigned short* __restrict__ WbI, unsigned short* __restrict__ WbO,
                       unsigned short* __restrict__ WbX, float* __restrict__ cwT) {
    int idx = blockIdx.x * 256 + threadIdx.x;
    if (idx < PREP_T1) {
        int g = idx * 4;
        float4 v = *(const float4*)(inproj_w + g);
        ushort4 o; o.x = f2b(v.x); o.y = f2b(v.y); o.z = f2b(v.z); o.w = f2b(v.w);
        *(ushort4*)(WbI + g) = o;
        return;
    }
    if (idx < PREP_T2) {
        int g = (idx - PREP_T1) * 4;
        float4 v = *(const float4*)(outproj_w + g);
        ushort4 o; o.x = f2b(v.x); o.y = f2b(v.y); o.z = f2b(v.z); o.w = f2b(v.w);
        *(ushort4*)(WbO + g) = o;
        return;
    }
    if (idx < PREP_T3) {
        int q = idx - PREP_T2;                 // 2*48*512
        int l = q / (48 * 512), r = (q >> 9) % 48, cc = q & 511;
        WbX[q] = (r < 33) ? f2b(xproj_w[(size_t)(l * 33 + r) * 512 + cc]) : (unsigned short)0;
        return;
    }
    if (idx < PREP_T4) {
        int q = idx - PREP_T3;                 // 2*4*512
        int l = q >> 11, k = (q >> 9) & 3, d = q & 511;
        cwT[q] = conv_w[(size_t)(l * DI + d) * 4 + k];
    }
}

// ----------------- input proj + fused layer-0 LN (block = one token)
__global__ __launch_bounds__(256) void k_inproj(
    const float* __restrict__ z, const float* __restrict__ w,
    const float* __restrict__ bias, const float* __restrict__ gam,
    const float* __restrict__ bet, float* __restrict__ x,
    unsigned short* __restrict__ xln) {
    int i = blockIdx.x, m = threadIdx.x;
    int lane = m & 63, wid = m >> 6;
    float4 zv = *(const float4*)(z + (size_t)i * 4);
    float4 wv = *(const float4*)(w + (size_t)m * 4);
    float r = bias[m];
    r = fmaf(zv.x, wv.x, r);
    r = fmaf(zv.y, wv.y, r);
    r = fmaf(zv.z, wv.z, r);
    r = fmaf(zv.w, wv.w, r);
    x[(size_t)i * DM + m] = r;
    // block LN over 256 channels
    __shared__ float red[8];
    float s = r, q = r * r;
    #pragma unroll
    for (int k = 32; k; k >>= 1) { s += __shfl_xor(s, k, 64); q += __shfl_xor(q, k, 64); }
    if (lane == 0) { red[wid] = s; red[4 + wid] = q; }
    __syncthreads();
    float st = red[0] + red[1] + red[2] + red[3];
    float qt = red[4] + red[5] + red[6] + red[7];
    float mu = st * (1.0f / DM);
    float rs = rsqrtf(qt * (1.0f / DM) - mu * mu + EPSF);
    xln[(size_t)i * DM + m] = f2b((r - mu) * rs * gam[m] + bet[m]);
}

// -------------------------------------------- fused row-LN -> bf16 (per wave)
__global__ void k_lnrow(const float* __restrict__ x, const float* __restrict__ gam,
                        const float* __restrict__ bet, unsigned short* __restrict__ xln) {
    int lane = threadIdx.x & 63, wid = threadIdx.x >> 6;
    int i = blockIdx.x * 4 + wid;
    float4 v = *(const float4*)(x + (size_t)i * DM + lane * 4);
    float s = v.x + v.y + v.z + v.w;
    float q = v.x * v.x + v.y * v.y + v.z * v.z + v.w * v.w;
    #pragma unroll
    for (int m = 32; m; m >>= 1) { s += __shfl_xor(s, m, 64); q += __shfl_xor(q, m, 64); }
    float mu = s * (1.0f / DM);
    float rs = rsqrtf(q * (1.0f / DM) - mu * mu + EPSF);
    float4 g4 = *(const float4*)(gam + lane * 4);
    float4 b4 = *(const float4*)(bet + lane * 4);
    ushort4 o;
    o.x = f2b((v.x - mu) * rs * g4.x + b4.x);
    o.y = f2b((v.y - mu) * rs * g4.y + b4.y);
    o.z = f2b((v.z - mu) * rs * g4.z + b4.z);
    o.w = f2b((v.w - mu) * rs * g4.w + b4.w);
    *(ushort4*)(xln + (size_t)i * DM + lane * 4) = o;
}

// ------------------------------------- GEMM1 (MFMA): [xp|z] = xln @ WbI^T
__global__ __launch_bounds__(256) void k_gemm1(
    const unsigned short* __restrict__ A, const unsigned short* __restrict__ W,
    unsigned short* __restrict__ xpb, unsigned short* __restrict__ zbb) {
    __shared__ unsigned short As[128 * 32];
    __shared__ unsigned short Bs[128 * 32];
    int tid = threadIdx.x, lane = tid & 63, wid = tid >> 6;
    int tileN = blockIdx.x & 7, tileM = blockIdx.x >> 3;
    int i0 = tileM * 128, n0 = tileN * 128;
    f32x4 acc[4][4];
    #pragma unroll
    for (int mi = 0; mi < 4; mi++)
        #pragma unroll
        for (int ni = 0; ni < 4; ni++) acc[mi][ni] = (f32x4){0.f, 0.f, 0.f, 0.f};

    int srow = (wid << 5) + (lane >> 2);
    int sblk = lane & 3;
    const unsigned short* ga = A + (size_t)(i0 + srow) * 256 + sblk * 8;
    const unsigned short* gb = W + (size_t)(n0 + srow) * 256 + sblk * 8;
    unsigned short* la = As + (wid << 5) * 32;
    unsigned short* lb = Bs + (wid << 5) * 32;
    int ar = lane & 15, ab = lane >> 4;
    const short8* pa = (const short8*)(As + ((wid >> 1) * 64 + ar) * 32 + ab * 8);
    const short8* pb = (const short8*)(Bs + ((wid & 1) * 64 + ar) * 32 + ab * 8);

    for (int k0 = 0; k0 < 256; k0 += 32) {
        gload_lds16(ga + k0,            la);
        gload_lds16(ga + k0 + 16 * 256, la + 16 * 32);
        gload_lds16(gb + k0,            lb);
        gload_lds16(gb + k0 + 16 * 256, lb + 16 * 32);
        __syncthreads();
        short8 a[4], b[4];
        #pragma unroll
        for (int mi = 0; mi < 4; mi++) a[mi] = pa[mi * 64];
        #pragma unroll
        for (int ni = 0; ni < 4; ni++) b[ni] = pb[ni * 64];
        #pragma unroll
        for (int mi = 0; mi < 4; mi++)
            #pragma unroll
            for (int ni = 0; ni < 4; ni++)
                acc[mi][ni] = __builtin_amdgcn_mfma_f32_16x16x32_bf16(a[mi], b[ni], acc[mi][ni], 0, 0, 0);
        __syncthreads();
    }
    int wr = wid >> 1, wc = wid & 1;
    int rbase = i0 + wr * 64 + (lane >> 4) * 4;
    int cbase = n0 + wc * 64 + (lane & 15);
    unsigned short* dst = (n0 < 512) ? xpb : zbb;
    int coff = (n0 < 512) ? cbase : cbase - 512;
    #pragma unroll
    for (int mi = 0; mi < 4; mi++)
        #pragma unroll
        for (int ni = 0; ni < 4; ni++)
            #pragma unroll
            for (int j = 0; j < 4; j++)
                dst[(size_t)(rbase + mi * 16 + j) * 512 + coff + ni * 16] = f2b(acc[mi][ni][j]);
}

// ---------------- depthwise causal conv + SiLU -> bf16 (rolling window, 8 tok/thread)
__global__ void k_conv(const unsigned short* __restrict__ xpb, const float* __restrict__ cwT,
                       const float* __restrict__ cb, unsigned short* __restrict__ xcb) {
    int g = blockIdx.x * 256 + threadIdx.x;     // NTOK/8 * 128 threads
    int tg = g >> 7, dq = g & 127;
    int d = dq * 4;
    int i0 = tg * 8;
    float4 w0 = *(const float4*)(cwT + 0 * DI + d);
    float4 w1 = *(const float4*)(cwT + 1 * DI + d);
    float4 w2 = *(const float4*)(cwT + 2 * DI + d);
    float4 w3 = *(const float4*)(cwT + 3 * DI + d);
    float4 bi = *(const float4*)(cb + d);
    float4 x0, x1, x2;
    if ((i0 & (SEQL - 1)) != 0) {
        x0 = b4f(*(const ushort4*)(xpb + (size_t)(i0 - 3) * DI + d));
        x1 = b4f(*(const ushort4*)(xpb + (size_t)(i0 - 2) * DI + d));
        x2 = b4f(*(const ushort4*)(xpb + (size_t)(i0 - 1) * DI + d));
    } else {
        x0 = x1 = x2 = make_float4(0.f, 0.f, 0.f, 0.f);
    }
    #pragma unroll
    for (int tt = 0; tt < 8; tt++) {
        float4 xc = b4f(*(const ushort4*)(xpb + (size_t)(i0 + tt) * DI + d));
        float4 a = bi;
        a.x = fmaf(w0.x, x0.x, a.x); a.y = fmaf(w0.y, x0.y, a.y);
        a.z = fmaf(w0.z, x0.z, a.z); a.w = fmaf(w0.w, x0.w, a.w);
        a.x = fmaf(w1.x, x1.x, a.x); a.y = fmaf(w1.y, x1.y, a.y);
        a.z = fmaf(w1.z, x1.z, a.z); a.w = fmaf(w1.w, x1.w, a.w);
        a.x = fmaf(w2.x, x2.x, a.x); a.y = fmaf(w2.y, x2.y, a.y);
        a.z = fmaf(w2.z, x2.z, a.z); a.w = fmaf(w2.w, x2.w, a.w);
        a.x = fmaf(w3.x, xc.x, a.x); a.y = fmaf(w3.y, xc.y, a.y);
        a.z = fmaf(w3.z, xc.z, a.z); a.w = fmaf(w3.w, xc.w, a.w);
        ushort4 o;
        o.x = f2b(siluf_(a.x)); o.y = f2b(siluf_(a.y));
        o.z = f2b(siluf_(a.z)); o.w = f2b(siluf_(a.w));
        *(ushort4*)(xcb + (size_t)(i0 + tt) * DI + d) = o;
        x0 = x1; x1 = x2; x2 = xc;
    }
}

// --------------------- xproj (MFMA): ssm = xcb @ WX_pad^T (N=48, rows>=33 dead)
__global__ __launch_bounds__(256) void k_xprojm(
    const unsigned short* __restrict__ A, const unsigned short* __restrict__ W,
    float* __restrict__ Bm, float* __restrict__ Cm, float* __restrict__ dtr) {
    __shared__ unsigned short As[128 * 32];
    __shared__ unsigned short Bs[48 * 32];
    int tid = threadIdx.x, lane = tid & 63, wid = tid >> 6;
    int i0 = blockIdx.x * 128;
    f32x4 acc[2][3];
    #pragma unroll
    for (int mi = 0; mi < 2; mi++)
        #pragma unroll
        for (int ni = 0; ni < 3; ni++) acc[mi][ni] = (f32x4){0.f, 0.f, 0.f, 0.f};

    int srow = lane >> 2, sblk = lane & 3;
    const unsigned short* ga = A + (size_t)(i0 + (wid << 5) + srow) * 512 + sblk * 8;
    unsigned short* la = As + (wid << 5) * 32;
    const unsigned short* gb = W + (size_t)((wid << 4) + srow) * 512 + sblk * 8;
    unsigned short* lb = Bs + (wid << 4) * 32;
    int ar = lane & 15, ab = lane >> 4;

    for (int k0 = 0; k0 < 512; k0 += 32) {
        gload_lds16(ga + k0,            la);
        gload_lds16(ga + k0 + 16 * 512, la + 16 * 32);
        if (wid < 3) gload_lds16(gb + k0, lb);
        __syncthreads();
        short8 a[2], b[3];
        #pragma unroll
        for (int mi = 0; mi < 2; mi++)
            a[mi] = *(const short8*)(As + ((wid << 5) + mi * 16 + ar) * 32 + ab * 8);
        #pragma unroll
        for (int ni = 0; ni < 3; ni++)
            b[ni] = *(const short8*)(Bs + (ni * 16 + ar) * 32 + ab * 8);
        #pragma unroll
        for (int mi = 0; mi < 2; mi++)
            #pragma unroll
            for (int ni = 0; ni < 3; ni++)
                acc[mi][ni] = __builtin_amdgcn_mfma_f32_16x16x32_bf16(a[mi], b[ni], acc[mi][ni], 0, 0, 0);
        __syncthreads();
    }
    #pragma unroll
    for (int mi = 0; mi < 2; mi++)
        #pragma unroll
        for (int ni = 0; ni < 3; ni++)
            #pragma unroll
            for (int j = 0; j < 4; j++) {
                int row = i0 + (wid << 5) + mi * 16 + (lane >> 4) * 4 + j;
                int ng = ni * 16 + (lane & 15);
                float v = acc[mi][ni][j];
                if (ng < 16)       Bm[(size_t)row * DS + ng] = v;
                else if (ng < 32)  Cm[(size_t)row * DS + ng - 16] = v;
                else if (ng == 32) dtr[row] = v;
            }
}

// ---- scan phase 1: chunk-local end states. x-chunk staged in LDS (async)
__global__ __launch_bounds__(256, 4) void k_scan1(
    const unsigned short* __restrict__ xcb, const float* __restrict__ Bm,
    const float* __restrict__ dtr, const float* __restrict__ dw,
    const float* __restrict__ db, float* __restrict__ hend, float* __restrict__ dtc) {
    __shared__ unsigned short Xsh[TC][256];     // 16 KB
    __shared__ float Bsh[TC][16];
    __shared__ float dtl[TC];
    int tid = threadIdx.x;
    int blk = blockIdx.x;                       // ((b*NCH)+c)*2 + half
    int half = blk & 1, c = (blk >> 1) & (NCH - 1), b = blk >> 8;
    int d = half * 256 + tid;
    int i0 = (b << 12) + c * TC;
    {   // async stage x: wave w covers rows 2w,2w+1 per call; 4 calls = 32 rows
        int lane = tid & 63, wid = tid >> 6;
        const unsigned short* gsrc = xcb + (size_t)(i0 + wid * 2 + (lane >> 5)) * DI
                                   + half * 256 + (lane & 31) * 8;
        unsigned short* ldst = &Xsh[wid * 2][0];
        #pragma unroll
        for (int r = 0; r < 4; r++)
            gload_lds16(gsrc + (size_t)r * 8 * DI, ldst + r * 8 * 256);
    }
    if (tid < TC) dtl[tid] = dtr[i0 + tid];
    if (tid < TC * 4) {
        int tt = tid >> 2, ss = (tid & 3) * 4;
        *(float4*)(&Bsh[tt][ss]) = *(const float4*)(Bm + (size_t)(i0 + tt) * DS + ss);
    }
    __syncthreads();
    float dwd = dw[d], dbd = db[d];
    float4 h0 = make_float4(0.f,0.f,0.f,0.f), h1 = h0, h2 = h0, h3 = h0;
    float dts = 0.0f;
    #pragma unroll 2
    for (int t = 0; t < TC; t++) {
        float dt, p;
        dt_p_(fmaf(dtl[t], dwd, dbd), dt, p);
        dts += dt;
        float xv = b2f(Xsh[t][tid]);
        float dtx = dt * xv;
        float p2 = p * p, p3 = p2 * p, p4 = p2 * p2;
        float p5 = p4 * p, p6 = p4 * p2, p7 = p4 * p3, p8 = p4 * p4;
        float p9 = p8 * p, p10 = p8 * p2, p11 = p8 * p3, p12 = p8 * p4;
        float p13 = p8 * p5, p14 = p8 * p6, p15 = p8 * p7, p16 = p8 * p8;
        float4 B0 = *(const float4*)(&Bsh[t][0]);
        float4 B1 = *(const float4*)(&Bsh[t][4]);
        float4 B2 = *(const float4*)(&Bsh[t][8]);
        float4 B3 = *(const float4*)(&Bsh[t][12]);
        h0.x = fmaf(p,   h0.x, dtx * B0.x); h0.y = fmaf(p2,  h0.y, dtx * B0.y);
        h0.z = fmaf(p3,  h0.z, dtx * B0.z); h0.w = fmaf(p4,  h0.w, dtx * B0.w);
        h1.x = fmaf(p5,  h1.x, dtx * B1.x); h1.y = fmaf(p6,  h1.y, dtx * B1.y);
        h1.z = fmaf(p7,  h1.z, dtx * B1.z); h1.w = fmaf(p8,  h1.w, dtx * B1.w);
        h2.x = fmaf(p9,  h2.x, dtx * B2.x); h2.y = fmaf(p10, h2.y, dtx * B2.y);
        h2.z = fmaf(p11, h2.z, dtx * B2.z); h2.w = fmaf(p12, h2.w, dtx * B2.w);
        h3.x = fmaf(p13, h3.x, dtx * B3.x); h3.y = fmaf(p14, h3.y, dtx * B3.y);
        h3.z = fmaf(p15, h3.z, dtx * B3.z); h3.w = fmaf(p16, h3.w, dtx * B3.w);
    }
    size_t hb = ((size_t)(b * DI + d) * NCH + c) * DS;
    *(float4*)(hend + hb + 0)  = h0;
    *(float4*)(hend + hb + 4)  = h1;
    *(float4*)(hend + hb + 8)  = h2;
    *(float4*)(hend + hb + 12) = h3;
    dtc[(size_t)(b * DI + d) * NCH + c] = dts;
}

// ------------- scan phase 2: propagate chunk-entry states; thread per (b,d,s)
__global__ void k_scan2(float* __restrict__ hend, const float* __restrict__ dtc) {
    int g = blockIdx.x * 256 + threadIdx.x;     // BATCH*DI*DS = 65536
    int s = g & 15, dd = (g >> 4) & 511, b = g >> 13;
    size_t base = (size_t)(b * DI + dd) * NCH;
    float hin = 0.0f;
    float kneg = -(float)(s + 1);
    #pragma unroll 4
    for (int c = 0; c < NCH; c++) {
        size_t a = (base + c) * DS + s;
        float tmp = hend[a];
        float pb = __expf(kneg * dtc[base + c]);
        hend[a] = hin;
        hin = fmaf(pb, hin, tmp);
    }
}

// ---- scan phase 3: recompute from entry state + gate. x,z staged in LDS
__global__ __launch_bounds__(256, 4) void k_scan3(
    const unsigned short* __restrict__ xcb, const float* __restrict__ Bm,
    const float* __restrict__ Cm, const float* __restrict__ dtr,
    const float* __restrict__ dw, const float* __restrict__ db,
    const float* __restrict__ hend, const unsigned short* __restrict__ zbb,
    unsigned short* __restrict__ ygb) {
    __shared__ unsigned short Xsh[TC][256];     // 16 KB
    __shared__ unsigned short Zsh[TC][256];     // 16 KB
    __shared__ float Bsh[TC][16];
    __shared__ float Csh[TC][16];
    __shared__ float dtl[TC];
    int tid = threadIdx.x;
    int blk = blockIdx.x;
    int half = blk & 1, c = (blk >> 1) & (NCH - 1), b = blk >> 8;
    int d = half * 256 + tid;
    int i0 = (b << 12) + c * TC;
    {   // async stage x and z chunks
        int lane = tid & 63, wid = tid >> 6;
        size_t goff = (size_t)(i0 + wid * 2 + (lane >> 5)) * DI + half * 256 + (lane & 31) * 8;
        const unsigned short* gx = xcb + goff;
        const unsigned short* gz = zbb + goff;
        unsigned short* lx = &Xsh[wid * 2][0];
        unsigned short* lz = &Zsh[wid * 2][0];
        #pragma unroll
        for (int r = 0; r < 4; r++) {
            gload_lds16(gx + (size_t)r * 8 * DI, lx + r * 8 * 256);
            gload_lds16(gz + (size_t)r * 8 * DI, lz + r * 8 * 256);
        }
    }
    if (tid < TC) dtl[tid] = dtr[i0 + tid];
    if (tid < TC * 4) {
        int tt = tid >> 2, ss = (tid & 3) * 4;
        *(float4*)(&Bsh[tt][ss]) = *(const float4*)(Bm + (size_t)(i0 + tt) * DS + ss);
    } else if (tid < TC * 8) {
        int q = tid - TC * 4;
        int tt = q >> 2, ss = (q & 3) * 4;
        *(float4*)(&Csh[tt][ss]) = *(const float4*)(Cm + (size_t)(i0 + tt) * DS + ss);
    }
    __syncthreads();
    float dwd = dw[d], dbd = db[d];
    size_t hb = ((size_t)(b * DI + d) * NCH + c) * DS;
    float4 h0 = *(const float4*)(hend + hb + 0);
    float4 h1 = *(const float4*)(hend + hb + 4);
    float4 h2 = *(const float4*)(hend + hb + 8);
    float4 h3 = *(const float4*)(hend + hb + 12);
    unsigned short* yp = ygb + (size_t)i0 * DI + d;
    #pragma unroll 2
    for (int t = 0; t < TC; t++) {
        float dt, p;
        dt_p_(fmaf(dtl[t], dwd, dbd), dt, p);
        float xv = b2f(Xsh[t][tid]);
        float dtx = dt * xv;
        float p2 = p * p, p3 = p2 * p, p4 = p2 * p2;
        float p5 = p4 * p, p6 = p4 * p2, p7 = p4 * p3, p8 = p4 * p4;
        float p9 = p8 * p, p10 = p8 * p2, p11 = p8 * p3, p12 = p8 * p4;
        float p13 = p8 * p5, p14 = p8 * p6, p15 = p8 * p7, p16 = p8 * p8;
        float4 B0 = *(const float4*)(&Bsh[t][0]);
        float4 B1 = *(const float4*)(&Bsh[t][4]);
        float4 B2 = *(const float4*)(&Bsh[t][8]);
        float4 B3 = *(const float4*)(&Bsh[t][12]);
        h0.x = fmaf(p,   h0.x, dtx * B0.x); h0.y = fmaf(p2,  h0.y, dtx * B0.y);
        h0.z = fmaf(p3,  h0.z, dtx * B0.z); h0.w = fmaf(p4,  h0.w, dtx * B0.w);
        h1.x = fmaf(p5,  h1.x, dtx * B1.x); h1.y = fmaf(p6,  h1.y, dtx * B1.y);
        h1.z = fmaf(p7,  h1.z, dtx * B1.z); h1.w = fmaf(p8,  h1.w, dtx * B1.w);
        h2.x = fmaf(p9,  h2.x, dtx * B2.x); h2.y = fmaf(p10, h2.y, dtx * B2.y);
        h2.z = fmaf(p11, h2.z, dtx * B2.z); h2.w = fmaf(p12, h2.w, dtx * B2.w);
        h3.x = fmaf(p13, h3.x, dtx * B3.x); h3.y = fmaf(p14, h3.y, dtx * B3.y);
        h3.z = fmaf(p15, h3.z, dtx * B3.z); h3.w = fmaf(p16, h3.w, dtx * B3.w);
        float4 C0 = *(const float4*)(&Csh[t][0]);
        float4 C1 = *(const float4*)(&Csh[t][4]);
        float4 C2 = *(const float4*)(&Csh[t][8]);
        float4 C3 = *(const float4*)(&Csh[t][12]);
        float y = 0.0f;
        y = fmaf(h0.x, C0.x, y); y = fmaf(h0.y, C0.y, y);
        y = fmaf(h0.z, C0.z, y); y = fmaf(h0.w, C0.w, y);
        y = fmaf(h1.x, C1.x, y); y = fmaf(h1.y, C1.y, y);
        y = fmaf(h1.z, C1.z, y); y = fmaf(h1.w, C1.w, y);
        y = fmaf(h2.x, C2.x, y); y = fmaf(h2.y, C2.y, y);
        y = fmaf(h2.z, C2.z, y); y = fmaf(h2.w, C2.w, y);
        y = fmaf(h3.x, C3.x, y); y = fmaf(h3.y, C3.y, y);
        y = fmaf(h3.z, C3.z, y); y = fmaf(h3.w, C3.w, y);
        float z = b2f(Zsh[t][tid]);
        yp[(size_t)t * DI] = f2b(y * siluf_(z));
    }
}

// ----------------------- outproj (MFMA): x += ygb @ WbO^T  (residual add)
__global__ __launch_bounds__(256) void k_outproj(
    const unsigned short* __restrict__ A, const unsigned short* __restrict__ W,
    float* __restrict__ x) {
    __shared__ unsigned short As[128 * 32];
    __shared__ unsigned short Bs[128 * 32];
    int tid = threadIdx.x, lane = tid & 63, wid = tid >> 6;
    int tileN = blockIdx.x & 1, tileM = blockIdx.x >> 1;
    int i0 = tileM * 128, n0 = tileN * 128;
    f32x4 acc[4][4];
    #pragma unroll
    for (int mi = 0; mi < 4; mi++)
        #pragma unroll
        for (int ni = 0; ni < 4; ni++) acc[mi][ni] = (f32x4){0.f, 0.f, 0.f, 0.f};

    int srow = (wid << 5) + (lane >> 2);
    int sblk = lane & 3;
    const unsigned short* ga = A + (size_t)(i0 + srow) * 512 + sblk * 8;
    const unsigned short* gb = W + (size_t)(n0 + srow) * 512 + sblk * 8;
    unsigned short* la = As + (wid << 5) * 32;
    unsigned short* lb = Bs + (wid << 5) * 32;
    int ar = lane & 15, ab = lane >> 4;
    const short8* pa = (const short8*)(As + ((wid >> 1) * 64 + ar) * 32 + ab * 8);
    const short8* pb = (const short8*)(Bs + ((wid & 1) * 64 + ar) * 32 + ab * 8);

    for (int k0 = 0; k0 < 512; k0 += 32) {
        gload_lds16(ga + k0,            la);
        gload_lds16(ga + k0 + 16 * 512, la + 16 * 32);
        gload_lds16(gb + k0,            lb);
        gload_lds16(gb + k0 + 16 * 512, lb + 16 * 32);
        __syncthreads();
        short8 a[4], b[4];
        #pragma unroll
        for (int mi = 0; mi < 4; mi++) a[mi] = pa[mi * 64];
        #pragma unroll
        for (int ni = 0; ni < 4; ni++) b[ni] = pb[ni * 64];
        #pragma unroll
        for (int mi = 0; mi < 4; mi++)
            #pragma unroll
            for (int ni = 0; ni < 4; ni++)
                acc[mi][ni] = __builtin_amdgcn_mfma_f32_16x16x32_bf16(a[mi], b[ni], acc[mi][ni], 0, 0, 0);
        __syncthreads();
    }
    int wr = wid >> 1, wc = wid & 1;
    int rbase = i0 + wr * 64 + (lane >> 4) * 4;
    int cbase = n0 + wc * 64 + (lane & 15);
    #pragma unroll
    for (int mi = 0; mi < 4; mi++)
        #pragma unroll
        for (int ni = 0; ni < 4; ni++)
            #pragma unroll
            for (int j = 0; j < 4; j++) {
                size_t idx = (size_t)(rbase + mi * 16 + j) * DM + cbase + ni * 16;
                x[idx] += acc[mi][ni][j];
            }
}

// -------------------------------------------- final LN + output projection
__global__ void k_final(const float* __restrict__ x, const float* __restrict__ gam,
                        const float* __restrict__ bet, const float* __restrict__ w,
                        const float* __restrict__ bias, float* __restrict__ out) {
    int lane = threadIdx.x & 63, wid = threadIdx.x >> 6;
    int i = blockIdx.x * 4 + wid;
    float4 v = *(const float4*)(x + (size_t)i * DM + lane * 4);
    float s = v.x + v.y + v.z + v.w;
    float q = v.x * v.x + v.y * v.y + v.z * v.z + v.w * v.w;
    #pragma unroll
    for (int m = 32; m; m >>= 1) { s += __shfl_xor(s, m, 64); q += __shfl_xor(q, m, 64); }
    float mu = s * (1.0f / DM);
    float rs = rsqrtf(q * (1.0f / DM) - mu * mu + EPSF);
    float4 gg = *(const float4*)(gam + lane * 4);
    float4 bb = *(const float4*)(bet + lane * 4);
    float xn[4] = {(v.x - mu) * rs * gg.x + bb.x, (v.y - mu) * rs * gg.y + bb.y,
                   (v.z - mu) * rs * gg.z + bb.z, (v.w - mu) * rs * gg.w + bb.w};
    float4 w0 = *(const float4*)(w + lane * 4);
    float4 w1 = *(const float4*)(w + DM + lane * 4);
    float p0 = xn[0] * w0.x + xn[1] * w0.y + xn[2] * w0.z + xn[3] * w0.w;
    float p1 = xn[0] * w1.x + xn[1] * w1.y + xn[2] * w1.z + xn[3] * w1.w;
    #pragma unroll
    for (int m = 32; m; m >>= 1) { p0 += __shfl_xor(p0, m, 64); p1 += __shfl_xor(p1, m, 64); }
    if (lane == 0) {
        out[(size_t)i * 2]     = p0 + bias[0];
        out[(size_t)i * 2 + 1] = p1 + bias[1];
    }
}

// ---------------------------------------------------------------------------
extern "C" void kernel_launch(void* const* d_in, const int* in_sizes, int n_in,
                              void* d_out, int out_size, void* d_ws, size_t ws_size,
                              hipStream_t stream) {
    const float* z_seq     = (const float*)d_in[0];
    const float* ip_w      = (const float*)d_in[1];
    const float* ip_b      = (const float*)d_in[2];
    const float* norm_g    = (const float*)d_in[3];
    const float* norm_b    = (const float*)d_in[4];
    const float* inproj_w  = (const float*)d_in[5];
    const float* conv_w    = (const float*)d_in[6];
    const float* conv_b    = (const float*)d_in[7];
    const float* xproj_w   = (const float*)d_in[8];
    const float* dt_w      = (const float*)d_in[9];
    const float* dt_b      = (const float*)d_in[10];
    const float* outproj_w = (const float*)d_in[11];
    const float* onorm_g   = (const float*)d_in[12];
    const float* onorm_b   = (const float*)d_in[13];
    const float* op_w      = (const float*)d_in[14];
    const float* op_b      = (const float*)d_in[15];

    char* ws = (char*)d_ws;
    float* x    = (float*)(ws + OFF_X);
    unsigned short* xpb = (unsigned short*)(ws + OFF_XPB);
    unsigned short* zbb = (unsigned short*)(ws + OFF_ZBB);
    unsigned short* xcb = (unsigned short*)(ws + OFF_XCB);
    unsigned short* xln = (unsigned short*)(ws + OFF_XLN);
    float* Bmb  = (float*)(ws + OFF_B);
    float* Cmb  = (float*)(ws + OFF_C);
    float* dtrb = (float*)(ws + OFF_DTR);
    float* hend = (float*)(ws + OFF_HE);
    float* dtc  = (float*)(ws + OFF_DTC);
    unsigned short* WbI = (unsigned short*)(ws + OFF_WBI);
    unsigned short* WbO = (unsigned short*)(ws + OFF_WBO);
    unsigned short* WbX = (unsigned short*)(ws + OFF_WBX);
    float* cwT  = (float*)(ws + OFF_CWT);

    k_prep<<<PREP_T4 / 256, 256, 0, stream>>>(inproj_w, outproj_w, xproj_w, conv_w,
                                              WbI, WbO, WbX, cwT);
    // inproj + fused layer-0 LN
    k_inproj<<<NTOK, 256, 0, stream>>>(z_seq, ip_w, ip_b, norm_g, norm_b, x, xln);

    for (int l = 0; l < 2; l++) {
        if (l > 0)
            k_lnrow<<<NTOK / 4, 256, 0, stream>>>(x, norm_g + l * DM, norm_b + l * DM, xln);
        k_gemm1<<<(NTOK / 128) * 8, 256, 0, stream>>>(
            xln, WbI + (size_t)l * 2 * DI * DM, xpb, zbb);
        k_conv<<<(NTOK / 8) * 128 / 256, 256, 0, stream>>>(
            xpb, cwT + (size_t)l * 4 * DI, conv_b + (size_t)l * DI, xcb);
        k_xprojm<<<NTOK / 128, 256, 0, stream>>>(
            xcb, WbX + (size_t)l * 48 * DI, Bmb, Cmb, dtrb);
        k_scan1<<<BATCH * NCH * 2, 256, 0, stream>>>(
            xcb, Bmb, dtrb, dt_w + l * DI, dt_b + l * DI, hend, dtc);
        k_scan2<<<BATCH * DI * DS / 256, 256, 0, stream>>>(hend, dtc);
        k_scan3<<<BATCH * NCH * 2, 256, 0, stream>>>(
            xcb, Bmb, Cmb, dtrb, dt_w + l * DI, dt_b + l * DI, hend, zbb, xpb);
        k_outproj<<<(NTOK / 128) * 2, 256, 0, stream>>>(
            xpb, WbO + (size_t)l * DM * DI, x);
    }
    k_final<<<NTOK / 4, 256, 0, stream>>>(x, onorm_g, onorm_b, op_w, op_b, (float*)d_out);
}